// Round 5
// baseline (438.484 us; speedup 1.0000x reference)
//
#include <hip/hip_runtime.h>
#include <math.h>

#define DMODEL 256
#define NHEAD 8
#define NLVL 3
#define NPTS 4
#define HDIM 32
#define QLEN 10000
#define BATCH 4
#define NQ (BATCH * QLEN)

__device__ __forceinline__ float tanh_fast(float x)
{
    const float ax = fabsf(x);
    const float e  = __expf(-2.f * ax);
    const float t  = (1.f - e) / (1.f + e);
    return copysignf(t, x);
}

__device__ __forceinline__ unsigned short f2bf(float f)
{
    unsigned int u = __float_as_uint(f);
    u = (u + 0x7FFFu + ((u >> 16) & 1u)) >> 16;
    return (unsigned short)u;
}

__device__ __forceinline__ float bf2f(unsigned short s)
{
    return __uint_as_float(((unsigned int)s) << 16);
}

// ---------------------------------------------------------------------------
// K1: value projection -> bf16, all 3 levels in one grid.
// ---------------------------------------------------------------------------
__global__ __launch_bounds__(256) void vproj_kernel(
    const float* __restrict__ feat0, const float* __restrict__ feat1,
    const float* __restrict__ feat2, const float* __restrict__ Wv,
    const float* __restrict__ bv,
    unsigned short* __restrict__ v0, unsigned short* __restrict__ v1,
    unsigned short* __restrict__ v2)
{
    __shared__ float As[16 * 64];    // [kk][pos]
    __shared__ float Ws[16 * 256];   // [kk][col]

    const int bx = blockIdx.x;
    const int b  = blockIdx.y;

    const float* feat;
    unsigned short* vout;
    int HW, pos0;
    if (bx < 157)      { feat = feat0; vout = v0; HW = 10000; pos0 = bx * 64; }
    else if (bx < 197) { feat = feat1; vout = v1; HW = 2500;  pos0 = (bx - 157) * 64; }
    else               { feat = feat2; vout = v2; HW = 625;   pos0 = (bx - 197) * 64; }

    const int tid  = threadIdx.x;
    const int tp   = tid >> 5;
    const int tc   = tid & 31;

    float acc[8][8];
#pragma unroll
    for (int i = 0; i < 8; ++i)
#pragma unroll
        for (int j = 0; j < 8; ++j) acc[i][j] = 0.f;

    const float* fb = feat + (size_t)b * DMODEL * HW;

    for (int k0 = 0; k0 < 256; k0 += 16) {
#pragma unroll
        for (int it = 0; it < 4; ++it) {
            const int kk = (tid >> 6) + it * 4;
            const int p  = tid & 63;
            float va = 0.f;
            if (pos0 + p < HW) va = fb[(size_t)(k0 + kk) * HW + pos0 + p];
            As[kk * 64 + p] = va;
        }
#pragma unroll
        for (int kk = 0; kk < 16; ++kk)
            Ws[kk * 256 + tid] = Wv[(size_t)(k0 + kk) * 256 + tid];
        __syncthreads();

#pragma unroll
        for (int kk = 0; kk < 16; ++kk) {
            const float4 a0 = *(const float4*)&As[kk * 64 + tp * 8];
            const float4 a1 = *(const float4*)&As[kk * 64 + tp * 8 + 4];
            const float a[8] = {a0.x, a0.y, a0.z, a0.w, a1.x, a1.y, a1.z, a1.w};
            float w[8];
#pragma unroll
            for (int jj = 0; jj < 4; ++jj) {
                const float2 wv = *(const float2*)&Ws[kk * 256 + 2 * tc + 64 * jj];
                w[2 * jj]     = wv.x;
                w[2 * jj + 1] = wv.y;
            }
#pragma unroll
            for (int i = 0; i < 8; ++i)
#pragma unroll
                for (int j = 0; j < 8; ++j)
                    acc[i][j] = fmaf(a[i], w[j], acc[i][j]);
        }
        __syncthreads();
    }

    float bb[8];
#pragma unroll
    for (int jj = 0; jj < 4; ++jj) {
        const float2 bvv = *(const float2*)&bv[2 * tc + 64 * jj];
        bb[2 * jj]     = bvv.x;
        bb[2 * jj + 1] = bvv.y;
    }

    unsigned short* vb = vout + (size_t)b * HW * 256;
#pragma unroll
    for (int i = 0; i < 8; ++i) {
        const int p = pos0 + tp * 8 + i;
        if (p < HW) {
            unsigned int* vp = (unsigned int*)(vb + (size_t)p * 256);
#pragma unroll
            for (int jj = 0; jj < 4; ++jj) {
                const unsigned int lo = f2bf(acc[i][2 * jj]     + bb[2 * jj]);
                const unsigned int hi = f2bf(acc[i][2 * jj + 1] + bb[2 * jj + 1]);
                vp[tc + 32 * jj] = lo | (hi << 16);
            }
        }
    }
}

// ---------------------------------------------------------------------------
// K2: query-side GEMM + epilogue.  32 rows/block (1250 blocks), 256 threads:
// thread = (r0 = tid>>3 in 0..31, h = tid&7), owns row r0 with acc[36] =
// head-h's 24 offset + 12 attn logits.  W kept in LINEAR LDS layout [kk][288]
// (cols 0..191 = W_off, 192..287 = W_attn); per-head reads are 16B-aligned
// float4 with <=2-way bank aliasing.  Epilogue fully in registers.
// ---------------------------------------------------------------------------
__global__ __launch_bounds__(256) void qparam_kernel(
    const float* __restrict__ query, const float* __restrict__ ref,
    const float* __restrict__ Woff, const float* __restrict__ boff,
    const float* __restrict__ Wattn, const float* __restrict__ battn,
    float* __restrict__ params)
{
    __shared__ float Qs[16 * 36];    // [kk][r], stride 36
    __shared__ float WL[16 * 288];   // [kk][col] linear

    const int row0 = blockIdx.x * 32;
    const int tid  = threadIdx.x;
    const int h    = tid & 7;
    const int r0   = tid >> 3;       // 0..31

    float acc[36];
#pragma unroll
    for (int j = 0; j < 36; ++j) acc[j] = 0.f;

    // Q staging indices: 256 threads, float2 each: row sr, k-pair sk
    const int sr = tid >> 3;          // 0..31
    const int sk = (tid & 7) * 2;     // 0,2,..,14

    for (int k0 = 0; k0 < 256; k0 += 16) {
        // ---- stage Q[32][16] transposed ----
        {
            const float2 qv =
                *(const float2*)&query[(size_t)(row0 + sr) * 256 + k0 + sk];
            Qs[(sk + 0) * 36 + sr] = qv.x;
            Qs[(sk + 1) * 36 + sr] = qv.y;
        }
        // ---- stage W[16][288] linear, float4 coalesced ----
#pragma unroll
        for (int j = 0; j < 5; ++j) {
            const int g = tid + j * 256;           // float4 index, 0..1151
            if (j < 4 || g < 1152) {
                const int kk = g / 72;
                const int c4 = g - kk * 72;        // float4 within row
                float4 wv;
                if (c4 < 48)
                    wv = *(const float4*)&Woff[(size_t)(k0 + kk) * 192 + 4 * c4];
                else
                    wv = *(const float4*)&Wattn[(size_t)(k0 + kk) * 96 + 4 * (c4 - 48)];
                *(float4*)&WL[kk * 288 + 4 * c4] = wv;
            }
        }
        __syncthreads();

        // ---- FMA: 36 per kk ----
#pragma unroll
        for (int kk = 0; kk < 16; ++kk) {
            const float a0 = Qs[kk * 36 + r0];
            const float* wo = &WL[kk * 288 + h * 24];
            const float* wa = &WL[kk * 288 + 192 + h * 12];
#pragma unroll
            for (int u = 0; u < 6; ++u) {
                const float4 w4 = *(const float4*)&wo[4 * u];
                acc[4 * u + 0] = fmaf(a0, w4.x, acc[4 * u + 0]);
                acc[4 * u + 1] = fmaf(a0, w4.y, acc[4 * u + 1]);
                acc[4 * u + 2] = fmaf(a0, w4.z, acc[4 * u + 2]);
                acc[4 * u + 3] = fmaf(a0, w4.w, acc[4 * u + 3]);
            }
#pragma unroll
            for (int u = 0; u < 3; ++u) {
                const float4 w4 = *(const float4*)&wa[4 * u];
                acc[24 + 4 * u + 0] = fmaf(a0, w4.x, acc[24 + 4 * u + 0]);
                acc[24 + 4 * u + 1] = fmaf(a0, w4.y, acc[24 + 4 * u + 1]);
                acc[24 + 4 * u + 2] = fmaf(a0, w4.z, acc[24 + 4 * u + 2]);
                acc[24 + 4 * u + 3] = fmaf(a0, w4.w, acc[24 + 4 * u + 3]);
            }
        }
        __syncthreads();
    }

    // ---- epilogue (registers only) ----
    const int row = row0 + r0;

#pragma unroll
    for (int j = 0; j < 24; ++j) acc[j] += boff[h * 24 + j];
#pragma unroll
    for (int j = 0; j < 12; ++j) acc[24 + j] += battn[h * 12 + j];

    float m = acc[24];
#pragma unroll
    for (int j = 1; j < 12; ++j) m = fmaxf(m, acc[24 + j]);
    float s = 0.f;
    float al[12];
#pragma unroll
    for (int j = 0; j < 12; ++j) { al[j] = __expf(acc[24 + j] - m); s += al[j]; }
    const float inv = 1.f / s;

    const float refx = ref[(size_t)row * 2 + 0];
    const float refy = ref[(size_t)row * 2 + 1];

    float outv[36];
#pragma unroll
    for (int l = 0; l < 3; ++l) {
        const float Wl = (l == 0) ? 100.f : (l == 1) ? 50.f : 25.f;
#pragma unroll
        for (int p = 0; p < 4; ++p) {
            const int j = l * 4 + p;
            const float ox = 0.5f * tanh_fast(acc[l * 8 + p * 2 + 0]);
            const float oy = 0.5f * tanh_fast(acc[l * 8 + p * 2 + 1]);
            outv[3 * j + 0] = (refx + ox) * Wl - 0.5f;
            outv[3 * j + 1] = (refy + oy) * Wl - 0.5f;
            outv[3 * j + 2] = al[j] * inv;
        }
    }

    float4* pp = (float4*)(params + (size_t)row * 288 + h * 36);
#pragma unroll
    for (int u = 0; u < 9; ++u)
        pp[u] = make_float4(outv[4 * u + 0], outv[4 * u + 1],
                            outv[4 * u + 2], outv[4 * u + 3]);
}

// ---------------------------------------------------------------------------
// K3: sampler.  ONE WAVE = ONE QUERY.
// ---------------------------------------------------------------------------
__global__ __launch_bounds__(256) void sample_kernel(
    const float* __restrict__ params,
    const unsigned short* __restrict__ v0,
    const unsigned short* __restrict__ v1,
    const unsigned short* __restrict__ v2,
    float* __restrict__ outp)
{
    const int tid  = threadIdx.x;
    const int lane = tid & 63;
    const int q    = blockIdx.x * 4 + (tid >> 6);
    const int h    = lane >> 3;
    const int qd   = lane & 7;
    const int b    = q / QLEN;

    const float4* pp = (const float4*)(params + (size_t)q * 288 + h * 36);
    float f[36];
#pragma unroll
    for (int i = 0; i < 9; ++i) {
        const float4 v = pp[i];
        f[4 * i + 0] = v.x; f[4 * i + 1] = v.y;
        f[4 * i + 2] = v.z; f[4 * i + 3] = v.w;
    }

    float o0 = 0.f, o1 = 0.f, o2 = 0.f, o3 = 0.f;

#pragma unroll
    for (int l = 0; l < 3; ++l) {
        const int Wl = (l == 0) ? 100 : (l == 1) ? 50 : 25;
        const int Hl = Wl;
        const unsigned short* vb =
            (l == 0) ? v0 + (size_t)b * 10000 * 256 :
            (l == 1) ? v1 + (size_t)b * 2500  * 256 :
                       v2 + (size_t)b * 625   * 256;

        int   cidx[16];
        float cwt[16];
#pragma unroll
        for (int p = 0; p < 4; ++p) {
            const int j = l * 4 + p;
            const float x  = f[3 * j + 0];
            const float y  = f[3 * j + 1];
            const float aw = f[3 * j + 2];
            const float xf = floorf(x), yf = floorf(y);
            const int   x0i = (int)xf, y0i = (int)yf;
            const float wx = x - xf, wy = y - yf;
#pragma unroll
            for (int cy = 0; cy < 2; ++cy) {
#pragma unroll
                for (int cx = 0; cx < 2; ++cx) {
                    const int xi = x0i + cx, yi = y0i + cy;
                    const bool valid =
                        (xi >= 0) & (xi < Wl) & (yi >= 0) & (yi < Hl);
                    const int xc = min(max(xi, 0), Wl - 1);
                    const int yc = min(max(yi, 0), Hl - 1);
                    const float w = aw * (cx ? wx : 1.f - wx)
                                       * (cy ? wy : 1.f - wy);
                    cidx[p * 4 + cy * 2 + cx] = yc * Wl + xc;
                    cwt [p * 4 + cy * 2 + cx] = valid ? w : 0.f;
                }
            }
        }
#pragma unroll
        for (int k = 0; k < 16; ++k) {
            const ushort4 u = *(const ushort4*)(vb +
                (size_t)cidx[k] * 256 + h * 32 + qd * 4);
            const float cw = cwt[k];
            o0 = fmaf(cw, bf2f(u.x), o0);
            o1 = fmaf(cw, bf2f(u.y), o1);
            o2 = fmaf(cw, bf2f(u.z), o2);
            o3 = fmaf(cw, bf2f(u.w), o3);
        }
    }

    *(float4*)(outp + (size_t)q * 256 + lane * 4) = make_float4(o0, o1, o2, o3);
}

// ---------------------------------------------------------------------------
// K4: output projection (in-place on d_out).  32 rows/block, 1250 blocks.
// thread = (tp = tid>>5 owning rows tp*4..tp*4+3, tc = tid&31, cols tc+32j).
// ---------------------------------------------------------------------------
__global__ __launch_bounds__(256) void outproj_kernel(
    const float* __restrict__ A, const float* __restrict__ Wo,
    const float* __restrict__ bo, float* __restrict__ out)
{
    __shared__ float As[16 * 36];    // [kk][r]
    __shared__ float Ws[16 * 256];

    const int row0 = blockIdx.x * 32;
    const int tid  = threadIdx.x;
    const int tp   = tid >> 5;
    const int tc   = tid & 31;

    float acc[4][8];
#pragma unroll
    for (int i = 0; i < 4; ++i)
#pragma unroll
        for (int j = 0; j < 8; ++j) acc[i][j] = 0.f;

    const int sr = tid >> 3;          // 0..31
    const int sk = (tid & 7) * 2;     // 0,2,..,14

    for (int k0 = 0; k0 < 256; k0 += 16) {
        {
            const float2 av =
                *(const float2*)&A[(size_t)(row0 + sr) * 256 + k0 + sk];
            As[(sk + 0) * 36 + sr] = av.x;
            As[(sk + 1) * 36 + sr] = av.y;
        }
#pragma unroll
        for (int kk = 0; kk < 16; ++kk)
            Ws[kk * 256 + tid] = Wo[(size_t)(k0 + kk) * 256 + tid];
        __syncthreads();

#pragma unroll
        for (int kk = 0; kk < 16; ++kk) {
            const float4 a4 = *(const float4*)&As[kk * 36 + tp * 4];
            const float a[4] = {a4.x, a4.y, a4.z, a4.w};
            float w[8];
#pragma unroll
            for (int jj = 0; jj < 4; ++jj) {
                const float2 wv = *(const float2*)&Ws[kk * 256 + 2 * tc + 64 * jj];
                w[2 * jj]     = wv.x;
                w[2 * jj + 1] = wv.y;
            }
#pragma unroll
            for (int i = 0; i < 4; ++i)
#pragma unroll
                for (int j = 0; j < 8; ++j)
                    acc[i][j] = fmaf(a[i], w[j], acc[i][j]);
        }
        __syncthreads();
    }

    float bb[8];
#pragma unroll
    for (int jj = 0; jj < 4; ++jj) {
        const float2 bvv = *(const float2*)&bo[2 * tc + 64 * jj];
        bb[2 * jj]     = bvv.x;
        bb[2 * jj + 1] = bvv.y;
    }

#pragma unroll
    for (int i = 0; i < 4; ++i) {
        const int r = row0 + tp * 4 + i;
        unsigned long long base = (unsigned long long)r * 256;
#pragma unroll
        for (int jj = 0; jj < 4; ++jj) {
            out[base + 2 * tc + 64 * jj + 0] = acc[i][2 * jj]     + bb[2 * jj];
            out[base + 2 * tc + 64 * jj + 1] = acc[i][2 * jj + 1] + bb[2 * jj + 1];
        }
    }
}

// ---------------------------------------------------------------------------
extern "C" void kernel_launch(void* const* d_in, const int* in_sizes, int n_in,
                              void* d_out, int out_size, void* d_ws, size_t ws_size,
                              hipStream_t stream)
{
    const float* query  = (const float*)d_in[0];
    const float* value0 = (const float*)d_in[1];
    const float* value1 = (const float*)d_in[2];
    const float* value2 = (const float*)d_in[3];
    const float* refpts = (const float*)d_in[4];
    const float* Woff   = (const float*)d_in[5];
    const float* boff   = (const float*)d_in[6];
    const float* Wattn  = (const float*)d_in[7];
    const float* battn  = (const float*)d_in[8];
    const float* Wval   = (const float*)d_in[9];
    const float* bval   = (const float*)d_in[10];
    const float* Wout   = (const float*)d_in[11];
    const float* bout   = (const float*)d_in[12];
    float* out = (float*)d_out;

    // workspace: params (46.08 MB) + v bf16 (26.88 MB) = 72.96 MB
    float*          params = (float*)d_ws;
    unsigned short* v0 = (unsigned short*)(params + (size_t)NQ * 288);
    unsigned short* v1 = v0 + (size_t)BATCH * 10000 * 256;
    unsigned short* v2 = v1 + (size_t)BATCH * 2500  * 256;
    float*          outp = out;   // outproj is in-place

    vproj_kernel<<<dim3(207, BATCH), 256, 0, stream>>>(
        value0, value1, value2, Wval, bval, v0, v1, v2);

    qparam_kernel<<<NQ / 32, 256, 0, stream>>>(query, refpts, Woff, boff,
                                               Wattn, battn, params);

    sample_kernel<<<NQ / 4, 256, 0, stream>>>(params, v0, v1, v2, outp);

    outproj_kernel<<<NQ / 32, 256, 0, stream>>>(outp, Wout, bout, out);
}